// Round 18
// baseline (119.953 us; speedup 1.0000x reference)
//
#include <hip/hip_runtime.h>
#include <hip/hip_bf16.h>
#include <stdint.h>

#define D_MODEL 1024
#define NH 16
#define DK 64
#define BB 2
#define SS 2048
#define MROWS (BB*SS)  // 4096

typedef __attribute__((ext_vector_type(8))) short bf16x8;
typedef __attribute__((ext_vector_type(4))) float f32x4;

__device__ __forceinline__ short to_bf16(float f) {
  __hip_bfloat16 h = __float2bfloat16(f);
  union { __hip_bfloat16 b; short s; } u; u.b = h; return u.s;
}

__device__ __forceinline__ f32x4 mfma16(bf16x8 a, bf16x8 b, f32x4 c) {
  return __builtin_amdgcn_mfma_f32_16x16x32_bf16(a, b, c, 0, 0, 0);
}

__device__ __forceinline__ void gload_lds16(const void* g, void* l) {
  __builtin_amdgcn_global_load_lds(
      (const __attribute__((address_space(1))) unsigned int*)g,
      (__attribute__((address_space(3))) unsigned int*)l,
      16, 0, 0);
}

__device__ __forceinline__ float max3f(float a, float b, float c) {
  return fmaxf(fmaxf(a, b), c);  // clang fuses to v_max3_f32
}

// ---------------- merged f32 -> bf16 converts (one launch) -----------------
__global__ __launch_bounds__(256) void cvt7(const float* __restrict__ x0,
                                            const float* __restrict__ x1,
                                            const float* __restrict__ x2,
                                            const float* __restrict__ w0,
                                            const float* __restrict__ w1,
                                            const float* __restrict__ w2,
                                            const float* __restrict__ w3,
                                            short* __restrict__ y0,
                                            short* __restrict__ y1,
                                            short* __restrict__ y2,
                                            short* __restrict__ y3,
                                            short* __restrict__ y4,
                                            short* __restrict__ y5,
                                            short* __restrict__ y6) {
  const int z = blockIdx.z;
  const float* x; short* y; int n;
  switch (z) {
    case 0: x = x0; y = y0; n = MROWS * D_MODEL; break;
    case 1: x = x1; y = y1; n = MROWS * D_MODEL; break;
    case 2: x = x2; y = y2; n = MROWS * D_MODEL; break;
    case 3: x = w0; y = y3; n = D_MODEL * D_MODEL; break;
    case 4: x = w1; y = y4; n = D_MODEL * D_MODEL; break;
    case 5: x = w2; y = y5; n = D_MODEL * D_MODEL; break;
    default: x = w3; y = y6; n = D_MODEL * D_MODEL; break;
  }
  const int i = (blockIdx.x * 256 + threadIdx.x) * 4;
  if (i >= n) return;
  const float4 v = *(const float4*)(x + i);
  short4 o;
  o.x = to_bf16(v.x); o.y = to_bf16(v.y); o.z = to_bf16(v.z); o.w = to_bf16(v.w);
  *(short4*)(y + i) = o;
}

// ---------------- QKV projection (R17 structure, frozen) -------------------
__global__ __launch_bounds__(512) void gemm_qkv8(const short* __restrict__ X,
                                                 const short* __restrict__ Wq,
                                                 const short* __restrict__ Wk,
                                                 const short* __restrict__ Wv,
                                                 const float* __restrict__ bq,
                                                 const float* __restrict__ bk,
                                                 const float* __restrict__ bv,
                                                 short* __restrict__ Qh,
                                                 short* __restrict__ Kh,
                                                 short* __restrict__ VT) {
  constexpr int K = 1024, NKT = K / 64;
  __shared__ short Abuf[2][256 * 64];  // 64 KB
  __shared__ short Bbuf[2][256 * 64];  // 64 KB

  const int tid = threadIdx.x;
  const int w = tid >> 6, lane = tid & 63;
  const int wm = w >> 2, wn = w & 3;          // 2M x 4N wave grid
  const int fr = lane & 15, fg = lane >> 4;

  const int m0 = blockIdx.x * 256, n0 = blockIdx.y * 256;
  const int z = m0 >> 12;                     // 0:Q 1:K 2:V (4096-row slabs)
  const short* Wt   = z == 0 ? Wq : z == 1 ? Wk : Wv;
  const float* bias = z == 0 ? bq : z == 1 ? bk : bv;

  const int str = tid >> 3;   // staging row base 0..63
  const int stc = tid & 7;    // staging chunk 0..7 (16B each)

  f32x4 acc[8][4] = {};

#define QKV8_STAGE(buf, kt)                                                   \
  do {                                                                        \
    _Pragma("unroll") for (int p = 0; p < 4; ++p) {                           \
      const int row = p * 64 + str;                                           \
      const int cS = stc ^ (row & 7);                                         \
      gload_lds16(X  + (size_t)(m0 + row) * K + (kt) * 64 + cS * 8,           \
                  &Abuf[buf][row * 64 + stc * 8]);                            \
      gload_lds16(Wt + (size_t)(n0 + row) * K + (kt) * 64 + cS * 8,           \
                  &Bbuf[buf][row * 64 + stc * 8]);                            \
    }                                                                         \
  } while (0)

  QKV8_STAGE(0, 0);
  asm volatile("s_waitcnt vmcnt(0)" ::: "memory");
  __syncthreads();

  for (int kt = 0; kt < NKT; ++kt) {
    const int buf = kt & 1;
    if (kt + 1 < NKT) QKV8_STAGE(buf ^ 1, kt + 1);  // hides under whole tile

    const short* Ab = Abuf[buf];
    const short* Bb = Bbuf[buf];
#pragma unroll
    for (int kh = 0; kh < 2; ++kh) {
      const int rchunk = (((kh << 2) + fg) ^ (fr & 7)) << 3;
      bf16x8 bfr[4];
#pragma unroll
      for (int ni = 0; ni < 4; ++ni)
        bfr[ni] = *(const bf16x8*)(Bb + (wn * 64 + ni * 16 + fr) * 64 + rchunk);
#pragma unroll
      for (int mh = 0; mh < 2; ++mh) {
        bf16x8 af[4];
#pragma unroll
        for (int i = 0; i < 4; ++i)
          af[i] = *(const bf16x8*)(Ab + (wm * 128 + (mh * 4 + i) * 16 + fr) * 64 + rchunk);
        __builtin_amdgcn_s_setprio(1);
#pragma unroll
        for (int i = 0; i < 4; ++i)
#pragma unroll
          for (int ni = 0; ni < 4; ++ni)
            acc[mh * 4 + i][ni] = mfma16(af[i], bfr[ni], acc[mh * 4 + i][ni]);
        __builtin_amdgcn_s_setprio(0);
      }
    }
    asm volatile("s_waitcnt vmcnt(0)" ::: "memory");
    __syncthreads();
  }
#undef QKV8_STAGE

  const int zrow0 = m0 & 4095;
  const int b = zrow0 >> 11;
  const int sb = zrow0 & (SS - 1);

  if (z < 2) {
    const float scale = (z == 0) ? 0.18033688011112042f : 1.0f;  // 0.125*log2(e)
    short* dst = (z == 0) ? Qh : Kh;
#pragma unroll
    for (int mi = 0; mi < 8; ++mi)
#pragma unroll
      for (int ni = 0; ni < 4; ++ni) {
        const int col = n0 + wn * 64 + ni * 16 + fr;
        const float bval = bias[col];
        const int h = col >> 6, d = col & 63;
#pragma unroll
        for (int r = 0; r < 4; ++r) {
          const int s = sb + wm * 128 + mi * 16 + fg * 4 + r;
          dst[((size_t)(b * NH + h) * SS + s) * DK + d] =
              to_bf16((acc[mi][ni][r] + bval) * scale);
        }
      }
  } else {
    // V: s runs along acc[..][r] -> natural short4 stores into (b,h,d,s)
#pragma unroll
    for (int mi = 0; mi < 8; ++mi)
#pragma unroll
      for (int ni = 0; ni < 4; ++ni) {
        const int col = n0 + wn * 64 + ni * 16 + fr;
        const float bval = bias[col];
        const int h = col >> 6, d = col & 63;
        const int s0 = sb + wm * 128 + mi * 16 + fg * 4;
        short4 sv = {to_bf16(acc[mi][ni][0] + bval), to_bf16(acc[mi][ni][1] + bval),
                     to_bf16(acc[mi][ni][2] + bval), to_bf16(acc[mi][ni][3] + bval)};
        *(short4*)(VT + ((size_t)(b * NH + h) * DK + d) * SS + s0) = sv;
      }
  }
}

// ---------------- O-projection (R12 structure, unchanged) ------------------
__global__ __launch_bounds__(256) void gemm_out(const short* __restrict__ A,
                                                const short* __restrict__ Wt,
                                                const float* __restrict__ bias,
                                                float* __restrict__ Y) {
  constexpr int K = 1024, NSTEP = K / 32;
  __shared__ __align__(16) char pool[36864];
  const int tid = threadIdx.x;
  const int w = tid >> 6, lane = tid & 63;
  const int m0 = blockIdx.x * 128, n0 = blockIdx.y * 64;
  const int wm = w >> 1, wn = w & 1;
  const int fr = lane & 15, fg = lane >> 4;
  const int srow = tid >> 2;
  const int scolS = ((tid & 3) ^ ((srow >> 1) & 3)) * 8;
  const int scolD = (tid & 3) * 8;
  const int fcs = (fg ^ ((fr >> 1) & 3)) * 8;

  f32x4 acc[4][2] = {};

#define OUT_STAGE(buf, k0)                                                    \
  do {                                                                        \
    short* As_ = (short*)(pool + (buf) * 12288);                              \
    short* Bs_ = (short*)(pool + (buf) * 12288 + 8192);                       \
    _Pragma("unroll") for (int i = 0; i < 2; ++i) {                           \
      const int row = i * 64 + srow;                                          \
      gload_lds16(A + (size_t)(m0 + row) * K + (k0) + scolS,                  \
                  As_ + row * 32 + scolD);                                    \
    }                                                                         \
    gload_lds16(Wt + (size_t)(n0 + srow) * K + (k0) + scolS,                  \
                Bs_ + srow * 32 + scolD);                                     \
  } while (0)

  OUT_STAGE(0, 0);
  OUT_STAGE(1, 32);
  asm volatile("s_waitcnt vmcnt(3)" ::: "memory");
  __syncthreads();

  for (int t = 0; t < NSTEP; ++t) {
    if (t + 2 < NSTEP) OUT_STAGE((t + 2) % 3, (t + 2) * 32);

    const short* Ab = (const short*)(pool + (t % 3) * 12288);
    const short* Bb = (const short*)(pool + (t % 3) * 12288 + 8192);
    bf16x8 af[4], bfr[2];
#pragma unroll
    for (int i = 0; i < 4; ++i)
      af[i] = *(const bf16x8*)(Ab + (wm * 64 + i * 16 + fr) * 32 + fcs);
#pragma unroll
    for (int i = 0; i < 2; ++i)
      bfr[i] = *(const bf16x8*)(Bb + (wn * 32 + i * 16 + fr) * 32 + fcs);
    __builtin_amdgcn_s_setprio(1);
#pragma unroll
    for (int mi = 0; mi < 4; ++mi)
#pragma unroll
      for (int ni = 0; ni < 2; ++ni)
        acc[mi][ni] = mfma16(af[mi], bfr[ni], acc[mi][ni]);
    __builtin_amdgcn_s_setprio(0);

    if (t + 2 < NSTEP)
      asm volatile("s_waitcnt vmcnt(3)" ::: "memory");
    else
      asm volatile("s_waitcnt vmcnt(0)" ::: "memory");
    __syncthreads();
  }
#undef OUT_STAGE

#pragma unroll
  for (int mi = 0; mi < 4; ++mi)
#pragma unroll
    for (int ni = 0; ni < 2; ++ni) {
      const int col = n0 + wn * 32 + ni * 16 + fr;
      const float bval = bias[col];
#pragma unroll
      for (int r = 0; r < 4; ++r) {
        const int row = m0 + wm * 64 + mi * 16 + fg * 4 + r;
        Y[(size_t)row * D_MODEL + col] = acc[mi][ni][r] + bval;
      }
    }
}

// ---------------- causal flash attention: 4 blocks/CU, single-buffered -----
// 1024 blocks = 32 bh x 32 strips (64 q rows, 4 waves x 16). KVBLK=128.
// K and V SINGLE-buffered (consumed at opposite tile phases): per tile g:
// softmax_pv(g-1)[Vs] + QK(g)[Ks] -> barrier -> stage V(g)+K(g+1) ->
// vmcnt(0)+barrier. LDS 40 KB -> 4 blocks/CU (16 waves, 2x the TLP);
// the 4 independent convoys cover each other's stage drains.
// Per-CU balance: strip = bh-odd-complemented identity -> any co-resident
// quad {s,31-s,s,31-s} sums to 34 tiles.
__global__ __launch_bounds__(256, 4) void attn_kernel(const short* __restrict__ Qh,
                                                      const short* __restrict__ Kh,
                                                      const short* __restrict__ VT,
                                                      short* __restrict__ AO) {
  __shared__ short Ks[128 * 64];      // [key][d], swizzled, 16 KB
  __shared__ short Vs[64 * 128];      // [d][key], swizzled, 16 KB
  __shared__ short P_lds[4][16 * 64]; // wave-private P^T, 8 KB

  const int tid = threadIdx.x, w = tid >> 6, lane = tid & 63;
  const int fr = lane & 15, fg = lane >> 4;
  const int kr = fg * 4;
  const int swz = (fr & 7) << 4;

  // XCD swizzle + per-CU quad balance
  const int bid = blockIdx.x;
  const int lid = ((bid & 7) << 7) | (bid >> 3);
  const int bh = lid >> 5;      // 0..31
  const int i5 = lid & 31;
  const int O = (i5 & 1) ? (i5 >> 1) : (31 - (i5 >> 1));
  const int s = (bh & 1) ? (31 - O) : O;  // strip 0..31
  const int b = bh >> 4, h = bh & 15;
  const int qb = s * 64;
  const int T = (s + 2) >> 1;             // tiles of 128 keys
  const int koff = (s & 1) ? 64 : 0;      // diagonal in-tile offset

  const short* Qp = Qh + (size_t)bh * SS * DK;
  const short* Kp = Kh + (size_t)bh * SS * DK;
  const short* Vp = VT + (size_t)bh * DK * SS;

  // staging decomposition (256 threads)
  const int kst_r = tid >> 3, kst_c = tid & 7;    // K: 4 passes x 32 rows x 8 chunks
  const int vst_r = tid >> 4, vst_c = tid & 15;   // V: 4 passes x 16 rows x 16 chunks

  bf16x8 qf[2];
#pragma unroll
  for (int hh = 0; hh < 2; ++hh)
    qf[hh] = *(const bf16x8*)(Qp + (size_t)(qb + w * 16 + fr) * DK + hh * 32 + fg * 8);

  const short onev = (fr == 0) ? (short)0x3F80 : (short)0;
  const bf16x8 af4 = {onev, onev, onev, onev, onev, onev, onev, onev};

  f32x4 o[5] = {};   // d-tiles 0..3 + l-sum; O^T[d=t*16+kr+r][q=fr]
  float m_run = -1e30f;
  f32x4 st[8];       // S^T fragments, one tile live at a time

#define STAGE_K(kk0)                                                          \
  do {                                                                        \
    _Pragma("unroll") for (int p = 0; p < 4; ++p) {                           \
      const int row = p * 32 + kst_r;                                         \
      const int sc = kst_c ^ (row & 7);                                       \
      gload_lds16(Kp + (size_t)((kk0) + row) * DK + sc * 8,                   \
                  Ks + row * 64 + kst_c * 8);                                 \
    }                                                                         \
  } while (0)
#define STAGE_V(kk0)                                                          \
  do {                                                                        \
    _Pragma("unroll") for (int p = 0; p < 4; ++p) {                           \
      const int row = p * 16 + vst_r;                                         \
      const int sc = vst_c ^ (row & 7);                                       \
      gload_lds16(Vp + (size_t)row * SS + (kk0) + sc * 8,                     \
                  Vs + row * 128 + vst_c * 8);                                \
    }                                                                         \
  } while (0)

  // softmax + PV of the tile currently in st, V in Vs
  auto softmax_pv = [&]() {
    float mm[8];
#pragma unroll
    for (int i = 0; i < 8; ++i)
      mm[i] = fmaxf(fmaxf(st[i][0], st[i][1]), fmaxf(st[i][2], st[i][3]));
    float pmax = fmaxf(max3f(mm[0], mm[1], mm[2]),
                       fmaxf(max3f(mm[3], mm[4], mm[5]), fmaxf(mm[6], mm[7])));
    pmax = fmaxf(pmax, __shfl_xor(pmax, 16));
    pmax = fmaxf(pmax, __shfl_xor(pmax, 32));

    if (!__all(pmax <= m_run + 11.0f)) {
      const float mn = fmaxf(m_run, pmax);
      const float al = __builtin_amdgcn_exp2f(m_run - mn);
      m_run = mn;
#pragma unroll
      for (int t = 0; t < 5; ++t)
#pragma unroll
        for (int r = 0; r < 4; ++r) o[t][r] *= al;
    }

#pragma unroll
    for (int hf = 0; hf < 2; ++hf) {
      char* base = (char*)P_lds[w];
#pragma unroll
      for (int kt = 0; kt < 4; ++kt) {
        const int kk = hf * 4 + kt;
        short4 sv;
        sv.x = to_bf16(__builtin_amdgcn_exp2f(st[kk][0] - m_run));
        sv.y = to_bf16(__builtin_amdgcn_exp2f(st[kk][1] - m_run));
        sv.z = to_bf16(__builtin_amdgcn_exp2f(st[kk][2] - m_run));
        sv.w = to_bf16(__builtin_amdgcn_exp2f(st[kk][3] - m_run));
        *(short4*)(base + ((fr * 128 + kt * 32 + fg * 8) ^ swz)) = sv;
      }
      asm volatile("s_waitcnt lgkmcnt(0)" ::: "memory");

      const char* VsB = (const char*)Vs;
      __builtin_amdgcn_s_setprio(1);
#pragma unroll
      for (int c = 0; c < 2; ++c) {
        const bf16x8 pf = *(const bf16x8*)((const char*)P_lds[w] +
                                           ((fr * 128 + c * 64 + fg * 16) ^ swz));
#pragma unroll
        for (int t = 0; t < 4; ++t) {
          const bf16x8 vfb = *(const bf16x8*)(VsB + (t * 16 + fr) * 256 +
                                              ((hf * 128 + c * 64 + fg * 16) ^ swz));
          o[t] = mfma16(vfb, pf, o[t]);
        }
        o[4] = mfma16(af4, pf, o[4]);
      }
      __builtin_amdgcn_s_setprio(0);
    }
  };

  STAGE_K(0);
  asm volatile("s_waitcnt vmcnt(0)" ::: "memory");
  __syncthreads();

  for (int g = 0; g < T; ++g) {
    if (g > 0) softmax_pv();   // consumes st = S(g-1), Vs = V(g-1)

    // QK(g) from Ks
    {
      const char* KsB = (const char*)Ks;
      __builtin_amdgcn_s_setprio(1);
#pragma unroll
      for (int kt = 0; kt < 8; ++kt) {
        const bf16x8 k0f = *(const bf16x8*)(KsB + (kt * 16 + fr) * 128 + ((fg * 16) ^ swz));
        const bf16x8 k1f = *(const bf16x8*)(KsB + (kt * 16 + fr) * 128 + ((64 + fg * 16) ^ swz));
        f32x4 zz = {};
        zz = mfma16(k0f, qf[0], zz);
        zz = mfma16(k1f, qf[1], zz);
        st[kt] = zz;
      }
      __builtin_amdgcn_s_setprio(0);
    }
    if (g == T - 1) {  // diagonal tile: mask kk > koff + q_local
#pragma unroll
      for (int kt = 0; kt < 8; ++kt)
#pragma unroll
        for (int r = 0; r < 4; ++r)
          if (kt * 16 + kr + r > koff + w * 16 + fr) st[kt][r] = -1e30f;
    }

    __syncthreads();              // all waves done with Ks + Vs
    STAGE_V(g * 128);             // V(g) for the softmax_pv of next iter / epilogue
    if (g + 1 < T) STAGE_K((g + 1) * 128);
    asm volatile("s_waitcnt vmcnt(0)" ::: "memory");
    __syncthreads();
  }

  softmax_pv();                   // tile T-1
  const float l = __shfl(o[4][0], fr);
  const float inv = 1.0f / l;
  const int sq = qb + w * 16 + fr;
#pragma unroll
  for (int t = 0; t < 4; ++t) {
    short4 ov = {to_bf16(o[t][0] * inv), to_bf16(o[t][1] * inv),
                 to_bf16(o[t][2] * inv), to_bf16(o[t][3] * inv)};
    *(short4*)(AO + (size_t)(b * SS + sq) * D_MODEL + h * 64 + t * 16 + kr) = ov;
  }
#undef STAGE_K
#undef STAGE_V
}

extern "C" void kernel_launch(void* const* d_in, const int* in_sizes, int n_in,
                              void* d_out, int out_size, void* d_ws, size_t ws_size,
                              hipStream_t stream) {
  const float* q  = (const float*)d_in[0];
  const float* k  = (const float*)d_in[1];
  const float* v  = (const float*)d_in[2];
  const float* Wq = (const float*)d_in[4];
  const float* bq = (const float*)d_in[5];
  const float* Wk = (const float*)d_in[6];
  const float* bk = (const float*)d_in[7];
  const float* Wv = (const float*)d_in[8];
  const float* bv = (const float*)d_in[9];
  const float* Wo = (const float*)d_in[10];
  const float* bo = (const float*)d_in[11];

  char* ws = (char*)d_ws;
  const size_t MB = 1u << 20;
  short* Xq = (short*)(ws + 0 * MB);   // Xq/Xk/Xv contiguous -> merged 12288x1024
  short* Xk = (short*)(ws + 8 * MB);
  short* Xv = (short*)(ws + 16 * MB);
  short* Bq = (short*)(ws + 24 * MB);
  short* Bk = (short*)(ws + 26 * MB);
  short* Bv = (short*)(ws + 28 * MB);
  short* Bo = (short*)(ws + 30 * MB);
  short* Qh = (short*)(ws + 32 * MB);
  short* Kh = (short*)(ws + 40 * MB);
  short* VT = (short*)(ws + 48 * MB);
  short* AO = (short*)(ws + 56 * MB);

  cvt7<<<dim3(MROWS * D_MODEL / 1024, 1, 7), 256, 0, stream>>>(
      q, k, v, Wq, Wk, Wv, Wo, Xq, Xk, Xv, Bq, Bk, Bv, Bo);

  gemm_qkv8<<<dim3(3 * MROWS / 256, D_MODEL / 256), 512, 0, stream>>>(
      Xq, Bq, Bk, Bv, bq, bk, bv, Qh, Kh, VT);

  attn_kernel<<<dim3(1024), 256, 0, stream>>>(Qh, Kh, VT, AO);

  gemm_out<<<dim3(MROWS / 128, D_MODEL / 64), 256, 0, stream>>>(AO, Bo, bo, (float*)d_out);
}

// Round 19
// 119.052 us; speedup vs baseline: 1.0076x; 1.0076x over previous
//
#include <hip/hip_runtime.h>
#include <hip/hip_bf16.h>
#include <stdint.h>

#define D_MODEL 1024
#define NH 16
#define DK 64
#define BB 2
#define SS 2048
#define MROWS (BB*SS)  // 4096

typedef __attribute__((ext_vector_type(8))) short bf16x8;
typedef __attribute__((ext_vector_type(4))) float f32x4;

__device__ __forceinline__ short to_bf16(float f) {
  __hip_bfloat16 h = __float2bfloat16(f);
  union { __hip_bfloat16 b; short s; } u; u.b = h; return u.s;
}

__device__ __forceinline__ f32x4 mfma16(bf16x8 a, bf16x8 b, f32x4 c) {
  return __builtin_amdgcn_mfma_f32_16x16x32_bf16(a, b, c, 0, 0, 0);
}

__device__ __forceinline__ void gload_lds16(const void* g, void* l) {
  __builtin_amdgcn_global_load_lds(
      (const __attribute__((address_space(1))) unsigned int*)g,
      (__attribute__((address_space(3))) unsigned int*)l,
      16, 0, 0);
}

__device__ __forceinline__ float max3f(float a, float b, float c) {
  return fmaxf(fmaxf(a, b), c);  // clang fuses to v_max3_f32
}

// ---------------- merged f32 -> bf16 converts (one launch) -----------------
__global__ __launch_bounds__(256) void cvt7(const float* __restrict__ x0,
                                            const float* __restrict__ x1,
                                            const float* __restrict__ x2,
                                            const float* __restrict__ w0,
                                            const float* __restrict__ w1,
                                            const float* __restrict__ w2,
                                            const float* __restrict__ w3,
                                            short* __restrict__ y0,
                                            short* __restrict__ y1,
                                            short* __restrict__ y2,
                                            short* __restrict__ y3,
                                            short* __restrict__ y4,
                                            short* __restrict__ y5,
                                            short* __restrict__ y6) {
  const int z = blockIdx.z;
  const float* x; short* y; int n;
  switch (z) {
    case 0: x = x0; y = y0; n = MROWS * D_MODEL; break;
    case 1: x = x1; y = y1; n = MROWS * D_MODEL; break;
    case 2: x = x2; y = y2; n = MROWS * D_MODEL; break;
    case 3: x = w0; y = y3; n = D_MODEL * D_MODEL; break;
    case 4: x = w1; y = y4; n = D_MODEL * D_MODEL; break;
    case 5: x = w2; y = y5; n = D_MODEL * D_MODEL; break;
    default: x = w3; y = y6; n = D_MODEL * D_MODEL; break;
  }
  const int i = (blockIdx.x * 256 + threadIdx.x) * 4;
  if (i >= n) return;
  const float4 v = *(const float4*)(x + i);
  short4 o;
  o.x = to_bf16(v.x); o.y = to_bf16(v.y); o.z = to_bf16(v.z); o.w = to_bf16(v.w);
  *(short4*)(y + i) = o;
}

// ---------------- QKV projection (R17 deep pipeline + XCD swizzle) ---------
// Merged-M A (12288 x 1024). 256x256 tile, 8 waves, BK=64, double-buffered
// 128 KB LDS, one vmcnt(0)+barrier per K-tile (64 MFMA + 24 ds_read/wave).
// Bijective XCD swizzle (m204): blocks sharing a W panel land on one XCD.
__global__ __launch_bounds__(512) void gemm_qkv8(const short* __restrict__ X,
                                                 const short* __restrict__ Wq,
                                                 const short* __restrict__ Wk,
                                                 const short* __restrict__ Wv,
                                                 const float* __restrict__ bq,
                                                 const float* __restrict__ bk,
                                                 const float* __restrict__ bv,
                                                 short* __restrict__ Qh,
                                                 short* __restrict__ Kh,
                                                 short* __restrict__ VT) {
  constexpr int K = 1024, NKT = K / 64;
  __shared__ short Abuf[2][256 * 64];  // 64 KB
  __shared__ short Bbuf[2][256 * 64];  // 64 KB

  const int tid = threadIdx.x;
  const int w = tid >> 6, lane = tid & 63;
  const int wm = w >> 2, wn = w & 3;          // 2M x 4N wave grid
  const int fr = lane & 15, fg = lane >> 4;

  // bijective XCD swizzle over the 192-block linear id (24 contiguous per XCD)
  const int nb = gridDim.x * gridDim.y;                 // 192
  const int orig = blockIdx.y * gridDim.x + blockIdx.x; // x-fast linear id
  const int cpx = nb >> 3;                              // 24 (nb % 8 == 0)
  const int lid = (orig & 7) * cpx + (orig >> 3);
  const int bx = lid % gridDim.x, by = lid / gridDim.x;

  const int m0 = bx * 256, n0 = by * 256;
  const int z = m0 >> 12;                     // 0:Q 1:K 2:V (4096-row slabs)
  const short* Wt   = z == 0 ? Wq : z == 1 ? Wk : Wv;
  const float* bias = z == 0 ? bq : z == 1 ? bk : bv;

  const int str = tid >> 3;   // staging row base 0..63
  const int stc = tid & 7;    // staging chunk 0..7 (16B each)

  f32x4 acc[8][4] = {};

#define QKV8_STAGE(buf, kt)                                                   \
  do {                                                                        \
    _Pragma("unroll") for (int p = 0; p < 4; ++p) {                           \
      const int row = p * 64 + str;                                           \
      const int cS = stc ^ (row & 7);                                         \
      gload_lds16(X  + (size_t)(m0 + row) * K + (kt) * 64 + cS * 8,           \
                  &Abuf[buf][row * 64 + stc * 8]);                            \
      gload_lds16(Wt + (size_t)(n0 + row) * K + (kt) * 64 + cS * 8,           \
                  &Bbuf[buf][row * 64 + stc * 8]);                            \
    }                                                                         \
  } while (0)

  QKV8_STAGE(0, 0);
  asm volatile("s_waitcnt vmcnt(0)" ::: "memory");
  __syncthreads();

  for (int kt = 0; kt < NKT; ++kt) {
    const int buf = kt & 1;
    if (kt + 1 < NKT) QKV8_STAGE(buf ^ 1, kt + 1);  // hides under whole tile

    const short* Ab = Abuf[buf];
    const short* Bb = Bbuf[buf];
#pragma unroll
    for (int kh = 0; kh < 2; ++kh) {
      const int rchunk = (((kh << 2) + fg) ^ (fr & 7)) << 3;
      bf16x8 bfr[4];
#pragma unroll
      for (int ni = 0; ni < 4; ++ni)
        bfr[ni] = *(const bf16x8*)(Bb + (wn * 64 + ni * 16 + fr) * 64 + rchunk);
#pragma unroll
      for (int mh = 0; mh < 2; ++mh) {
        bf16x8 af[4];
#pragma unroll
        for (int i = 0; i < 4; ++i)
          af[i] = *(const bf16x8*)(Ab + (wm * 128 + (mh * 4 + i) * 16 + fr) * 64 + rchunk);
        __builtin_amdgcn_s_setprio(1);
#pragma unroll
        for (int i = 0; i < 4; ++i)
#pragma unroll
          for (int ni = 0; ni < 4; ++ni)
            acc[mh * 4 + i][ni] = mfma16(af[i], bfr[ni], acc[mh * 4 + i][ni]);
        __builtin_amdgcn_s_setprio(0);
      }
    }
    asm volatile("s_waitcnt vmcnt(0)" ::: "memory");
    __syncthreads();
  }
#undef QKV8_STAGE

  const int zrow0 = m0 & 4095;
  const int b = zrow0 >> 11;
  const int sb = zrow0 & (SS - 1);

  if (z < 2) {
    const float scale = (z == 0) ? 0.18033688011112042f : 1.0f;  // 0.125*log2(e)
    short* dst = (z == 0) ? Qh : Kh;
#pragma unroll
    for (int mi = 0; mi < 8; ++mi)
#pragma unroll
      for (int ni = 0; ni < 4; ++ni) {
        const int col = n0 + wn * 64 + ni * 16 + fr;
        const float bval = bias[col];
        const int h = col >> 6, d = col & 63;
#pragma unroll
        for (int r = 0; r < 4; ++r) {
          const int s = sb + wm * 128 + mi * 16 + fg * 4 + r;
          dst[((size_t)(b * NH + h) * SS + s) * DK + d] =
              to_bf16((acc[mi][ni][r] + bval) * scale);
        }
      }
  } else {
    // V: s runs along acc[..][r] -> natural short4 stores into (b,h,d,s)
#pragma unroll
    for (int mi = 0; mi < 8; ++mi)
#pragma unroll
      for (int ni = 0; ni < 4; ++ni) {
        const int col = n0 + wn * 64 + ni * 16 + fr;
        const float bval = bias[col];
        const int h = col >> 6, d = col & 63;
        const int s0 = sb + wm * 128 + mi * 16 + fg * 4;
        short4 sv = {to_bf16(acc[mi][ni][0] + bval), to_bf16(acc[mi][ni][1] + bval),
                     to_bf16(acc[mi][ni][2] + bval), to_bf16(acc[mi][ni][3] + bval)};
        *(short4*)(VT + ((size_t)(b * NH + h) * DK + d) * SS + s0) = sv;
      }
  }
}

// ---------------- O-projection (R12 structure) -----------------------------
__global__ __launch_bounds__(256) void gemm_out(const short* __restrict__ A,
                                                const short* __restrict__ Wt,
                                                const float* __restrict__ bias,
                                                float* __restrict__ Y) {
  constexpr int K = 1024, NSTEP = K / 32;
  __shared__ __align__(16) char pool[36864];
  const int tid = threadIdx.x;
  const int w = tid >> 6, lane = tid & 63;
  const int m0 = blockIdx.x * 128, n0 = blockIdx.y * 64;
  const int wm = w >> 1, wn = w & 1;
  const int fr = lane & 15, fg = lane >> 4;
  const int srow = tid >> 2;
  const int scolS = ((tid & 3) ^ ((srow >> 1) & 3)) * 8;
  const int scolD = (tid & 3) * 8;
  const int fcs = (fg ^ ((fr >> 1) & 3)) * 8;

  f32x4 acc[4][2] = {};

#define OUT_STAGE(buf, k0)                                                    \
  do {                                                                        \
    short* As_ = (short*)(pool + (buf) * 12288);                              \
    short* Bs_ = (short*)(pool + (buf) * 12288 + 8192);                       \
    _Pragma("unroll") for (int i = 0; i < 2; ++i) {                           \
      const int row = i * 64 + srow;                                          \
      gload_lds16(A + (size_t)(m0 + row) * K + (k0) + scolS,                  \
                  As_ + row * 32 + scolD);                                    \
    }                                                                         \
    gload_lds16(Wt + (size_t)(n0 + srow) * K + (k0) + scolS,                  \
                Bs_ + srow * 32 + scolD);                                     \
  } while (0)

  OUT_STAGE(0, 0);
  OUT_STAGE(1, 32);
  asm volatile("s_waitcnt vmcnt(3)" ::: "memory");
  __syncthreads();

  for (int t = 0; t < NSTEP; ++t) {
    if (t + 2 < NSTEP) OUT_STAGE((t + 2) % 3, (t + 2) * 32);

    const short* Ab = (const short*)(pool + (t % 3) * 12288);
    const short* Bb = (const short*)(pool + (t % 3) * 12288 + 8192);
    bf16x8 af[4], bfr[2];
#pragma unroll
    for (int i = 0; i < 4; ++i)
      af[i] = *(const bf16x8*)(Ab + (wm * 64 + i * 16 + fr) * 32 + fcs);
#pragma unroll
    for (int i = 0; i < 2; ++i)
      bfr[i] = *(const bf16x8*)(Bb + (wn * 32 + i * 16 + fr) * 32 + fcs);
    __builtin_amdgcn_s_setprio(1);
#pragma unroll
    for (int mi = 0; mi < 4; ++mi)
#pragma unroll
      for (int ni = 0; ni < 2; ++ni)
        acc[mi][ni] = mfma16(af[mi], bfr[ni], acc[mi][ni]);
    __builtin_amdgcn_s_setprio(0);

    if (t + 2 < NSTEP)
      asm volatile("s_waitcnt vmcnt(3)" ::: "memory");
    else
      asm volatile("s_waitcnt vmcnt(0)" ::: "memory");
    __syncthreads();
  }
#undef OUT_STAGE

#pragma unroll
  for (int mi = 0; mi < 4; ++mi)
#pragma unroll
    for (int ni = 0; ni < 2; ++ni) {
      const int col = n0 + wn * 32 + ni * 16 + fr;
      const float bval = bias[col];
#pragma unroll
      for (int r = 0; r < 4; ++r) {
        const int row = m0 + wm * 64 + mi * 16 + fg * 4 + r;
        Y[(size_t)row * D_MODEL + col] = acc[mi][ni][r] + bval;
      }
    }
}

// ---------------- causal flash attention (R14 structure, session best) -----
__global__ __launch_bounds__(256) void attn_kernel(const short* __restrict__ Qh,
                                                   const short* __restrict__ Kh,
                                                   const short* __restrict__ VT,
                                                   short* __restrict__ AO) {
  __shared__ short Ks[2][2][64 * 64];  // [buf][half][key][d], swizzled, 32 KB
  __shared__ short Vs[2][2][64 * 64];  // [buf][half][d][key], swizzled, 32 KB
  __shared__ short P_lds[4][16 * 64];  // wave-private P^T, 8 KB

  const int tid = threadIdx.x, w = tid >> 6, lane = tid & 63;
  const int fr = lane & 15, fg = lane >> 4;
  const int kr = fg * 4;
  const int swz = (fr & 7) << 4;

  const int bid = blockIdx.x;
  const int lid = ((bid & 7) << 6) | (bid >> 3);
  const int bh = lid >> 4;      // 0..31
  const int j = lid & 15;       // pair {j, 31-j}
  const int b = bh >> 4, h = bh & 15;

  const short* Qp = Qh + (size_t)bh * SS * DK;
  const short* Kp = Kh + (size_t)bh * SS * DK;
  const short* Vp = VT + (size_t)bh * DK * SS;

  const int sc_c = tid & 7;    // 16B chunk within 128B row
  const int sc_r = tid >> 3;   // row 0..31 (pass adds 32)

  const int T0 = (j + 2) >> 1;          // seg0 tiles; T1 = 17 - T0
  const int koff0 = j * 64 - (T0 - 1) * 128;          // 0 or 64
  const int koff1 = (31 - j) * 64 - (16 - T0) * 128;  // 64 or 0

  bf16x8 qf[2];
#pragma unroll
  for (int hh = 0; hh < 2; ++hh)
    qf[hh] = *(const bf16x8*)(Qp + (size_t)(j * 64 + w * 16 + fr) * DK + hh * 32 + fg * 8);

  const short onev = (fr == 0) ? (short)0x3F80 : (short)0;
  const bf16x8 af4 = {onev, onev, onev, onev, onev, onev, onev, onev};

  f32x4 o[5] = {};
  float m_run = -1e30f;
  f32x4 stA[8], stB[8];  // [half*4 + kt]

#define KK0(g) ((((g) < T0) ? (g) : ((g) - T0)) * 128)
#define STAGE_K(buf, kk0)                                                     \
  do {                                                                        \
    _Pragma("unroll") for (int hf = 0; hf < 2; ++hf)                          \
    _Pragma("unroll") for (int p = 0; p < 2; ++p) {                           \
      const int row = p * 32 + sc_r;                                          \
      const int sc = sc_c ^ (row & 7);                                        \
      gload_lds16(Kp + (size_t)((kk0) + hf * 64 + row) * DK + sc * 8,         \
                  &Ks[buf][hf][row * 64 + sc_c * 8]);                         \
    }                                                                         \
  } while (0)
#define STAGE_V(buf, kk0)                                                     \
  do {                                                                        \
    _Pragma("unroll") for (int hf = 0; hf < 2; ++hf)                          \
    _Pragma("unroll") for (int p = 0; p < 2; ++p) {                           \
      const int row = p * 32 + sc_r;                                          \
      const int sc = sc_c ^ (row & 7);                                        \
      gload_lds16(Vp + (size_t)row * SS + (kk0) + hf * 64 + sc * 8,           \
                  &Vs[buf][hf][row * 64 + sc_c * 8]);                         \
    }                                                                         \
  } while (0)

#define SOFTMAX_PV(ST, bufPrev)                                               \
  do {                                                                        \
    float mm[8];                                                              \
    _Pragma("unroll") for (int i = 0; i < 8; ++i)                             \
      mm[i] = fmaxf(fmaxf(ST[i][0], ST[i][1]), fmaxf(ST[i][2], ST[i][3]));    \
    float pmax = fmaxf(max3f(mm[0], mm[1], mm[2]),                            \
                       fmaxf(max3f(mm[3], mm[4], mm[5]), fmaxf(mm[6], mm[7]))); \
    pmax = fmaxf(pmax, __shfl_xor(pmax, 16));                                 \
    pmax = fmaxf(pmax, __shfl_xor(pmax, 32));                                 \
    if (!__all(pmax <= m_run + 11.0f)) {                                      \
      const float mn = fmaxf(m_run, pmax);                                    \
      const float al = __builtin_amdgcn_exp2f(m_run - mn);                    \
      m_run = mn;                                                             \
      _Pragma("unroll") for (int t = 0; t < 5; ++t)                           \
        _Pragma("unroll") for (int r = 0; r < 4; ++r) o[t][r] *= al;          \
    }                                                                         \
    _Pragma("unroll") for (int hf = 0; hf < 2; ++hf) {                        \
      char* base = (char*)P_lds[w];                                           \
      _Pragma("unroll") for (int kt = 0; kt < 4; ++kt) {                      \
        short4 sv;                                                            \
        sv.x = to_bf16(__builtin_amdgcn_exp2f(ST[hf * 4 + kt][0] - m_run));   \
        sv.y = to_bf16(__builtin_amdgcn_exp2f(ST[hf * 4 + kt][1] - m_run));   \
        sv.z = to_bf16(__builtin_amdgcn_exp2f(ST[hf * 4 + kt][2] - m_run));   \
        sv.w = to_bf16(__builtin_amdgcn_exp2f(ST[hf * 4 + kt][3] - m_run));   \
        *(short4*)(base + ((fr * 128 + kt * 32 + fg * 8) ^ swz)) = sv;        \
      }                                                                       \
      asm volatile("s_waitcnt lgkmcnt(0)" ::: "memory");                      \
      const char* VsB = (const char*)Vs[bufPrev][hf];                         \
      __builtin_amdgcn_s_setprio(1);                                          \
      _Pragma("unroll") for (int c = 0; c < 2; ++c) {                         \
        const bf16x8 pf = *(const bf16x8*)((const char*)P_lds[w] +            \
                                           ((fr * 128 + c * 64 + fg * 16) ^ swz)); \
        _Pragma("unroll") for (int t = 0; t < 4; ++t) {                       \
          const bf16x8 vfb = *(const bf16x8*)(VsB + (t * 16 + fr) * 128 +     \
                                              ((c * 64 + fg * 16) ^ swz));    \
          o[t] = mfma16(vfb, pf, o[t]);                                       \
        }                                                                     \
        o[4] = mfma16(af4, pf, o[4]);                                         \
      }                                                                       \
      __builtin_amdgcn_s_setprio(0);                                          \
    }                                                                         \
  } while (0)

#define STEP(CUR, PREV, g)                                                    \
  do {                                                                        \
    if ((g) == T0) {                                                          \
      _Pragma("unroll") for (int hh = 0; hh < 2; ++hh)                        \
        qf[hh] = *(const bf16x8*)(Qp + (size_t)((31 - j) * 64 + w * 16 + fr) * DK + hh * 32 + fg * 8); \
    }                                                                         \
    if ((g) + 1 < 17) STAGE_K(((g) + 1) & 1, KK0((g) + 1));                   \
    {                                                                         \
      __builtin_amdgcn_s_setprio(1);                                          \
      _Pragma("unroll") for (int hf = 0; hf < 2; ++hf) {                      \
        const char* KsB = (const char*)Ks[(g) & 1][hf];                       \
        _Pragma("unroll") for (int kt = 0; kt < 4; ++kt) {                    \
          const bf16x8 k0f = *(const bf16x8*)(KsB + (kt * 16 + fr) * 128 + ((fg * 16) ^ swz)); \
          const bf16x8 k1f = *(const bf16x8*)(KsB + (kt * 16 + fr) * 128 + ((64 + fg * 16) ^ swz)); \
          f32x4 zz = {};                                                      \
          zz = mfma16(k0f, qf[0], zz);                                        \
          zz = mfma16(k1f, qf[1], zz);                                        \
          CUR[hf * 4 + kt] = zz;                                              \
        }                                                                     \
      }                                                                       \
      __builtin_amdgcn_s_setprio(0);                                          \
    }                                                                         \
    if ((g) == T0 - 1 || (g) == 16) {                                         \
      const int koff = ((g) == 16) ? koff1 : koff0;                           \
      _Pragma("unroll") for (int hf = 0; hf < 2; ++hf)                        \
        _Pragma("unroll") for (int kt = 0; kt < 4; ++kt)                      \
          _Pragma("unroll") for (int r = 0; r < 4; ++r)                       \
            if (hf * 64 + kt * 16 + kr + r > koff + w * 16 + fr)              \
              CUR[hf * 4 + kt][r] = -1e30f;                                   \
    }                                                                         \
    if ((g) > 0) {                                                            \
      SOFTMAX_PV(PREV, ((g) - 1) & 1);                                        \
      if ((g) == T0) {                                                        \
        store_o(j * 64);                                                      \
        _Pragma("unroll") for (int t = 0; t < 5; ++t)                         \
          _Pragma("unroll") for (int r = 0; r < 4; ++r) o[t][r] = 0.f;        \
        m_run = -1e30f;                                                       \
      }                                                                       \
    }                                                                         \
    __syncthreads();                                                          \
    if ((g) + 1 < 17) {                                                       \
      STAGE_V(((g) + 1) & 1, KK0((g) + 1));                                   \
      asm volatile("s_waitcnt vmcnt(4)" ::: "memory");                        \
    } else {                                                                  \
      asm volatile("s_waitcnt vmcnt(0)" ::: "memory");                        \
    }                                                                         \
  } while (0)

  auto store_o = [&](int qbase) {
    const float l = __shfl(o[4][0], fr);
    const float inv = 1.0f / l;
    const int s = qbase + w * 16 + fr;
#pragma unroll
    for (int t = 0; t < 4; ++t) {
      short4 ov = {to_bf16(o[t][0] * inv), to_bf16(o[t][1] * inv),
                   to_bf16(o[t][2] * inv), to_bf16(o[t][3] * inv)};
      *(short4*)(AO + (size_t)(b * SS + s) * D_MODEL + h * 64 + t * 16 + kr) = ov;
    }
  };

  STAGE_K(0, 0);
  STAGE_V(0, 0);
  asm volatile("s_waitcnt vmcnt(0)" ::: "memory");
  __syncthreads();

  for (int gg = 0; gg < 16; gg += 2) {
    STEP(stA, stB, gg);
    STEP(stB, stA, gg + 1);
  }
  STEP(stA, stB, 16);

  // epilogue: tile 16 lives in stA (17 is odd)
  SOFTMAX_PV(stA, 0);
  store_o((31 - j) * 64);
#undef STEP
#undef SOFTMAX_PV
#undef STAGE_K
#undef STAGE_V
#undef KK0
}

extern "C" void kernel_launch(void* const* d_in, const int* in_sizes, int n_in,
                              void* d_out, int out_size, void* d_ws, size_t ws_size,
                              hipStream_t stream) {
  const float* q  = (const float*)d_in[0];
  const float* k  = (const float*)d_in[1];
  const float* v  = (const float*)d_in[2];
  const float* Wq = (const float*)d_in[4];
  const float* bq = (const float*)d_in[5];
  const float* Wk = (const float*)d_in[6];
  const float* bk = (const float*)d_in[7];
  const float* Wv = (const float*)d_in[8];
  const float* bv = (const float*)d_in[9];
  const float* Wo = (const float*)d_in[10];
  const float* bo = (const float*)d_in[11];

  char* ws = (char*)d_ws;
  const size_t MB = 1u << 20;
  short* Xq = (short*)(ws + 0 * MB);   // Xq/Xk/Xv contiguous -> merged 12288x1024
  short* Xk = (short*)(ws + 8 * MB);
  short* Xv = (short*)(ws + 16 * MB);
  short* Bq = (short*)(ws + 24 * MB);
  short* Bk = (short*)(ws + 26 * MB);
  short* Bv = (short*)(ws + 28 * MB);
  short* Bo = (short*)(ws + 30 * MB);
  short* Qh = (short*)(ws + 32 * MB);
  short* Kh = (short*)(ws + 40 * MB);
  short* VT = (short*)(ws + 48 * MB);
  short* AO = (short*)(ws + 56 * MB);

  cvt7<<<dim3(MROWS * D_MODEL / 1024, 1, 7), 256, 0, stream>>>(
      q, k, v, Wq, Wk, Wv, Wo, Xq, Xk, Xv, Bq, Bk, Bv, Bo);

  gemm_qkv8<<<dim3(3 * MROWS / 256, D_MODEL / 256), 512, 0, stream>>>(
      Xq, Bq, Bk, Bv, bq, bk, bv, Qh, Kh, VT);

  attn_kernel<<<dim3(512), 256, 0, stream>>>(Qh, Kh, VT, AO);

  gemm_out<<<dim3(MROWS / 128, D_MODEL / 64), 256, 0, stream>>>(AO, Bo, bo, (float*)d_out);
}

// Round 20
// 117.411 us; speedup vs baseline: 1.0216x; 1.0140x over previous
//
#include <hip/hip_runtime.h>
#include <hip/hip_bf16.h>
#include <stdint.h>

#define D_MODEL 1024
#define NH 16
#define DK 64
#define BB 2
#define SS 2048
#define MROWS (BB*SS)  // 4096

typedef __attribute__((ext_vector_type(8))) short bf16x8;
typedef __attribute__((ext_vector_type(4))) float f32x4;

__device__ __forceinline__ short to_bf16(float f) {
  __hip_bfloat16 h = __float2bfloat16(f);
  union { __hip_bfloat16 b; short s; } u; u.b = h; return u.s;
}

__device__ __forceinline__ f32x4 mfma16(bf16x8 a, bf16x8 b, f32x4 c) {
  return __builtin_amdgcn_mfma_f32_16x16x32_bf16(a, b, c, 0, 0, 0);
}

__device__ __forceinline__ void gload_lds16(const void* g, void* l) {
  __builtin_amdgcn_global_load_lds(
      (const __attribute__((address_space(1))) unsigned int*)g,
      (__attribute__((address_space(3))) unsigned int*)l,
      16, 0, 0);
}

__device__ __forceinline__ float max3f(float a, float b, float c) {
  return fmaxf(fmaxf(a, b), c);  // clang fuses to v_max3_f32
}

// ---------------- merged f32 -> bf16 converts (one launch) -----------------
__global__ __launch_bounds__(256) void cvt7(const float* __restrict__ x0,
                                            const float* __restrict__ x1,
                                            const float* __restrict__ x2,
                                            const float* __restrict__ w0,
                                            const float* __restrict__ w1,
                                            const float* __restrict__ w2,
                                            const float* __restrict__ w3,
                                            short* __restrict__ y0,
                                            short* __restrict__ y1,
                                            short* __restrict__ y2,
                                            short* __restrict__ y3,
                                            short* __restrict__ y4,
                                            short* __restrict__ y5,
                                            short* __restrict__ y6) {
  const int z = blockIdx.z;
  const float* x; short* y; int n;
  switch (z) {
    case 0: x = x0; y = y0; n = MROWS * D_MODEL; break;
    case 1: x = x1; y = y1; n = MROWS * D_MODEL; break;
    case 2: x = x2; y = y2; n = MROWS * D_MODEL; break;
    case 3: x = w0; y = y3; n = D_MODEL * D_MODEL; break;
    case 4: x = w1; y = y4; n = D_MODEL * D_MODEL; break;
    case 5: x = w2; y = y5; n = D_MODEL * D_MODEL; break;
    default: x = w3; y = y6; n = D_MODEL * D_MODEL; break;
  }
  const int i = (blockIdx.x * 256 + threadIdx.x) * 4;
  if (i >= n) return;
  const float4 v = *(const float4*)(x + i);
  short4 o;
  o.x = to_bf16(v.x); o.y = to_bf16(v.y); o.z = to_bf16(v.z); o.w = to_bf16(v.w);
  *(short4*)(y + i) = o;
}

// ---------------- QKV projection (R17 deep pipeline, session best) ---------
// Merged-M A (12288 x 1024). 256x256 tile, 8 waves, BK=64, double-buffered
// 128 KB LDS, one vmcnt(0)+barrier per K-tile (64 MFMA + 24 ds_read/wave).
// NO XCD swizzle: the x-fast linear dispatch already gives W-panel L2 reuse
// (R19's remap raised FETCH 37->53 MB and cost 1.5 us).
__global__ __launch_bounds__(512) void gemm_qkv8(const short* __restrict__ X,
                                                 const short* __restrict__ Wq,
                                                 const short* __restrict__ Wk,
                                                 const short* __restrict__ Wv,
                                                 const float* __restrict__ bq,
                                                 const float* __restrict__ bk,
                                                 const float* __restrict__ bv,
                                                 short* __restrict__ Qh,
                                                 short* __restrict__ Kh,
                                                 short* __restrict__ VT) {
  constexpr int K = 1024, NKT = K / 64;
  __shared__ short Abuf[2][256 * 64];  // 64 KB
  __shared__ short Bbuf[2][256 * 64];  // 64 KB

  const int tid = threadIdx.x;
  const int w = tid >> 6, lane = tid & 63;
  const int wm = w >> 2, wn = w & 3;          // 2M x 4N wave grid
  const int fr = lane & 15, fg = lane >> 4;

  const int m0 = blockIdx.x * 256, n0 = blockIdx.y * 256;
  const int z = m0 >> 12;                     // 0:Q 1:K 2:V (4096-row slabs)
  const short* Wt   = z == 0 ? Wq : z == 1 ? Wk : Wv;
  const float* bias = z == 0 ? bq : z == 1 ? bk : bv;

  const int str = tid >> 3;   // staging row base 0..63
  const int stc = tid & 7;    // staging chunk 0..7 (16B each)

  f32x4 acc[8][4] = {};

#define QKV8_STAGE(buf, kt)                                                   \
  do {                                                                        \
    _Pragma("unroll") for (int p = 0; p < 4; ++p) {                           \
      const int row = p * 64 + str;                                           \
      const int cS = stc ^ (row & 7);                                         \
      gload_lds16(X  + (size_t)(m0 + row) * K + (kt) * 64 + cS * 8,           \
                  &Abuf[buf][row * 64 + stc * 8]);                            \
      gload_lds16(Wt + (size_t)(n0 + row) * K + (kt) * 64 + cS * 8,           \
                  &Bbuf[buf][row * 64 + stc * 8]);                            \
    }                                                                         \
  } while (0)

  QKV8_STAGE(0, 0);
  asm volatile("s_waitcnt vmcnt(0)" ::: "memory");
  __syncthreads();

  for (int kt = 0; kt < NKT; ++kt) {
    const int buf = kt & 1;
    if (kt + 1 < NKT) QKV8_STAGE(buf ^ 1, kt + 1);  // hides under whole tile

    const short* Ab = Abuf[buf];
    const short* Bb = Bbuf[buf];
#pragma unroll
    for (int kh = 0; kh < 2; ++kh) {
      const int rchunk = (((kh << 2) + fg) ^ (fr & 7)) << 3;
      bf16x8 bfr[4];
#pragma unroll
      for (int ni = 0; ni < 4; ++ni)
        bfr[ni] = *(const bf16x8*)(Bb + (wn * 64 + ni * 16 + fr) * 64 + rchunk);
#pragma unroll
      for (int mh = 0; mh < 2; ++mh) {
        bf16x8 af[4];
#pragma unroll
        for (int i = 0; i < 4; ++i)
          af[i] = *(const bf16x8*)(Ab + (wm * 128 + (mh * 4 + i) * 16 + fr) * 64 + rchunk);
        __builtin_amdgcn_s_setprio(1);
#pragma unroll
        for (int i = 0; i < 4; ++i)
#pragma unroll
          for (int ni = 0; ni < 4; ++ni)
            acc[mh * 4 + i][ni] = mfma16(af[i], bfr[ni], acc[mh * 4 + i][ni]);
        __builtin_amdgcn_s_setprio(0);
      }
    }
    asm volatile("s_waitcnt vmcnt(0)" ::: "memory");
    __syncthreads();
  }
#undef QKV8_STAGE

  const int zrow0 = m0 & 4095;
  const int b = zrow0 >> 11;
  const int sb = zrow0 & (SS - 1);

  if (z < 2) {
    const float scale = (z == 0) ? 0.18033688011112042f : 1.0f;  // 0.125*log2(e)
    short* dst = (z == 0) ? Qh : Kh;
#pragma unroll
    for (int mi = 0; mi < 8; ++mi)
#pragma unroll
      for (int ni = 0; ni < 4; ++ni) {
        const int col = n0 + wn * 64 + ni * 16 + fr;
        const float bval = bias[col];
        const int h = col >> 6, d = col & 63;
#pragma unroll
        for (int r = 0; r < 4; ++r) {
          const int s = sb + wm * 128 + mi * 16 + fg * 4 + r;
          dst[((size_t)(b * NH + h) * SS + s) * DK + d] =
              to_bf16((acc[mi][ni][r] + bval) * scale);
        }
      }
  } else {
    // V: s runs along acc[..][r] -> natural short4 stores into (b,h,d,s)
#pragma unroll
    for (int mi = 0; mi < 8; ++mi)
#pragma unroll
      for (int ni = 0; ni < 4; ++ni) {
        const int col = n0 + wn * 64 + ni * 16 + fr;
        const float bval = bias[col];
        const int h = col >> 6, d = col & 63;
        const int s0 = sb + wm * 128 + mi * 16 + fg * 4;
        short4 sv = {to_bf16(acc[mi][ni][0] + bval), to_bf16(acc[mi][ni][1] + bval),
                     to_bf16(acc[mi][ni][2] + bval), to_bf16(acc[mi][ni][3] + bval)};
        *(short4*)(VT + ((size_t)(b * NH + h) * DK + d) * SS + s0) = sv;
      }
  }
}

// ---------------- O-projection (R12 structure) -----------------------------
__global__ __launch_bounds__(256) void gemm_out(const short* __restrict__ A,
                                                const short* __restrict__ Wt,
                                                const float* __restrict__ bias,
                                                float* __restrict__ Y) {
  constexpr int K = 1024, NSTEP = K / 32;
  __shared__ __align__(16) char pool[36864];
  const int tid = threadIdx.x;
  const int w = tid >> 6, lane = tid & 63;
  const int m0 = blockIdx.x * 128, n0 = blockIdx.y * 64;
  const int wm = w >> 1, wn = w & 1;
  const int fr = lane & 15, fg = lane >> 4;
  const int srow = tid >> 2;
  const int scolS = ((tid & 3) ^ ((srow >> 1) & 3)) * 8;
  const int scolD = (tid & 3) * 8;
  const int fcs = (fg ^ ((fr >> 1) & 3)) * 8;

  f32x4 acc[4][2] = {};

#define OUT_STAGE(buf, k0)                                                    \
  do {                                                                        \
    short* As_ = (short*)(pool + (buf) * 12288);                              \
    short* Bs_ = (short*)(pool + (buf) * 12288 + 8192);                       \
    _Pragma("unroll") for (int i = 0; i < 2; ++i) {                           \
      const int row = i * 64 + srow;                                          \
      gload_lds16(A + (size_t)(m0 + row) * K + (k0) + scolS,                  \
                  As_ + row * 32 + scolD);                                    \
    }                                                                         \
    gload_lds16(Wt + (size_t)(n0 + srow) * K + (k0) + scolS,                  \
                Bs_ + srow * 32 + scolD);                                     \
  } while (0)

  OUT_STAGE(0, 0);
  OUT_STAGE(1, 32);
  asm volatile("s_waitcnt vmcnt(3)" ::: "memory");
  __syncthreads();

  for (int t = 0; t < NSTEP; ++t) {
    if (t + 2 < NSTEP) OUT_STAGE((t + 2) % 3, (t + 2) * 32);

    const short* Ab = (const short*)(pool + (t % 3) * 12288);
    const short* Bb = (const short*)(pool + (t % 3) * 12288 + 8192);
    bf16x8 af[4], bfr[2];
#pragma unroll
    for (int i = 0; i < 4; ++i)
      af[i] = *(const bf16x8*)(Ab + (wm * 64 + i * 16 + fr) * 32 + fcs);
#pragma unroll
    for (int i = 0; i < 2; ++i)
      bfr[i] = *(const bf16x8*)(Bb + (wn * 32 + i * 16 + fr) * 32 + fcs);
    __builtin_amdgcn_s_setprio(1);
#pragma unroll
    for (int mi = 0; mi < 4; ++mi)
#pragma unroll
      for (int ni = 0; ni < 2; ++ni)
        acc[mi][ni] = mfma16(af[mi], bfr[ni], acc[mi][ni]);
    __builtin_amdgcn_s_setprio(0);

    if (t + 2 < NSTEP)
      asm volatile("s_waitcnt vmcnt(3)" ::: "memory");
    else
      asm volatile("s_waitcnt vmcnt(0)" ::: "memory");
    __syncthreads();
  }
#undef OUT_STAGE

#pragma unroll
  for (int mi = 0; mi < 4; ++mi)
#pragma unroll
    for (int ni = 0; ni < 2; ++ni) {
      const int col = n0 + wn * 32 + ni * 16 + fr;
      const float bval = bias[col];
#pragma unroll
      for (int r = 0; r < 4; ++r) {
        const int row = m0 + wm * 64 + mi * 16 + fg * 4 + r;
        Y[(size_t)row * D_MODEL + col] = acc[mi][ni][r] + bval;
      }
    }
}

// ---------------- causal flash attention (R14 structure, session best) -----
__global__ __launch_bounds__(256) void attn_kernel(const short* __restrict__ Qh,
                                                   const short* __restrict__ Kh,
                                                   const short* __restrict__ VT,
                                                   short* __restrict__ AO) {
  __shared__ short Ks[2][2][64 * 64];  // [buf][half][key][d], swizzled, 32 KB
  __shared__ short Vs[2][2][64 * 64];  // [buf][half][d][key], swizzled, 32 KB
  __shared__ short P_lds[4][16 * 64];  // wave-private P^T, 8 KB

  const int tid = threadIdx.x, w = tid >> 6, lane = tid & 63;
  const int fr = lane & 15, fg = lane >> 4;
  const int kr = fg * 4;
  const int swz = (fr & 7) << 4;

  const int bid = blockIdx.x;
  const int lid = ((bid & 7) << 6) | (bid >> 3);
  const int bh = lid >> 4;      // 0..31
  const int j = lid & 15;       // pair {j, 31-j}
  const int b = bh >> 4, h = bh & 15;

  const short* Qp = Qh + (size_t)bh * SS * DK;
  const short* Kp = Kh + (size_t)bh * SS * DK;
  const short* Vp = VT + (size_t)bh * DK * SS;

  const int sc_c = tid & 7;    // 16B chunk within 128B row
  const int sc_r = tid >> 3;   // row 0..31 (pass adds 32)

  const int T0 = (j + 2) >> 1;          // seg0 tiles; T1 = 17 - T0
  const int koff0 = j * 64 - (T0 - 1) * 128;          // 0 or 64
  const int koff1 = (31 - j) * 64 - (16 - T0) * 128;  // 64 or 0

  bf16x8 qf[2];
#pragma unroll
  for (int hh = 0; hh < 2; ++hh)
    qf[hh] = *(const bf16x8*)(Qp + (size_t)(j * 64 + w * 16 + fr) * DK + hh * 32 + fg * 8);

  const short onev = (fr == 0) ? (short)0x3F80 : (short)0;
  const bf16x8 af4 = {onev, onev, onev, onev, onev, onev, onev, onev};

  f32x4 o[5] = {};
  float m_run = -1e30f;
  f32x4 stA[8], stB[8];  // [half*4 + kt]

#define KK0(g) ((((g) < T0) ? (g) : ((g) - T0)) * 128)
#define STAGE_K(buf, kk0)                                                     \
  do {                                                                        \
    _Pragma("unroll") for (int hf = 0; hf < 2; ++hf)                          \
    _Pragma("unroll") for (int p = 0; p < 2; ++p) {                           \
      const int row = p * 32 + sc_r;                                          \
      const int sc = sc_c ^ (row & 7);                                        \
      gload_lds16(Kp + (size_t)((kk0) + hf * 64 + row) * DK + sc * 8,         \
                  &Ks[buf][hf][row * 64 + sc_c * 8]);                         \
    }                                                                         \
  } while (0)
#define STAGE_V(buf, kk0)                                                     \
  do {                                                                        \
    _Pragma("unroll") for (int hf = 0; hf < 2; ++hf)                          \
    _Pragma("unroll") for (int p = 0; p < 2; ++p) {                           \
      const int row = p * 32 + sc_r;                                          \
      const int sc = sc_c ^ (row & 7);                                        \
      gload_lds16(Vp + (size_t)row * SS + (kk0) + hf * 64 + sc * 8,           \
                  &Vs[buf][hf][row * 64 + sc_c * 8]);                         \
    }                                                                         \
  } while (0)

#define SOFTMAX_PV(ST, bufPrev)                                               \
  do {                                                                        \
    float mm[8];                                                              \
    _Pragma("unroll") for (int i = 0; i < 8; ++i)                             \
      mm[i] = fmaxf(fmaxf(ST[i][0], ST[i][1]), fmaxf(ST[i][2], ST[i][3]));    \
    float pmax = fmaxf(max3f(mm[0], mm[1], mm[2]),                            \
                       fmaxf(max3f(mm[3], mm[4], mm[5]), fmaxf(mm[6], mm[7]))); \
    pmax = fmaxf(pmax, __shfl_xor(pmax, 16));                                 \
    pmax = fmaxf(pmax, __shfl_xor(pmax, 32));                                 \
    if (!__all(pmax <= m_run + 11.0f)) {                                      \
      const float mn = fmaxf(m_run, pmax);                                    \
      const float al = __builtin_amdgcn_exp2f(m_run - mn);                    \
      m_run = mn;                                                             \
      _Pragma("unroll") for (int t = 0; t < 5; ++t)                           \
        _Pragma("unroll") for (int r = 0; r < 4; ++r) o[t][r] *= al;          \
    }                                                                         \
    _Pragma("unroll") for (int hf = 0; hf < 2; ++hf) {                        \
      char* base = (char*)P_lds[w];                                           \
      _Pragma("unroll") for (int kt = 0; kt < 4; ++kt) {                      \
        short4 sv;                                                            \
        sv.x = to_bf16(__builtin_amdgcn_exp2f(ST[hf * 4 + kt][0] - m_run));   \
        sv.y = to_bf16(__builtin_amdgcn_exp2f(ST[hf * 4 + kt][1] - m_run));   \
        sv.z = to_bf16(__builtin_amdgcn_exp2f(ST[hf * 4 + kt][2] - m_run));   \
        sv.w = to_bf16(__builtin_amdgcn_exp2f(ST[hf * 4 + kt][3] - m_run));   \
        *(short4*)(base + ((fr * 128 + kt * 32 + fg * 8) ^ swz)) = sv;        \
      }                                                                       \
      asm volatile("s_waitcnt lgkmcnt(0)" ::: "memory");                      \
      const char* VsB = (const char*)Vs[bufPrev][hf];                         \
      __builtin_amdgcn_s_setprio(1);                                          \
      _Pragma("unroll") for (int c = 0; c < 2; ++c) {                         \
        const bf16x8 pf = *(const bf16x8*)((const char*)P_lds[w] +            \
                                           ((fr * 128 + c * 64 + fg * 16) ^ swz)); \
        _Pragma("unroll") for (int t = 0; t < 4; ++t) {                       \
          const bf16x8 vfb = *(const bf16x8*)(VsB + (t * 16 + fr) * 128 +     \
                                              ((c * 64 + fg * 16) ^ swz));    \
          o[t] = mfma16(vfb, pf, o[t]);                                       \
        }                                                                     \
        o[4] = mfma16(af4, pf, o[4]);                                         \
      }                                                                       \
      __builtin_amdgcn_s_setprio(0);                                          \
    }                                                                         \
  } while (0)

#define STEP(CUR, PREV, g)                                                    \
  do {                                                                        \
    if ((g) == T0) {                                                          \
      _Pragma("unroll") for (int hh = 0; hh < 2; ++hh)                        \
        qf[hh] = *(const bf16x8*)(Qp + (size_t)((31 - j) * 64 + w * 16 + fr) * DK + hh * 32 + fg * 8); \
    }                                                                         \
    if ((g) + 1 < 17) STAGE_K(((g) + 1) & 1, KK0((g) + 1));                   \
    {                                                                         \
      __builtin_amdgcn_s_setprio(1);                                          \
      _Pragma("unroll") for (int hf = 0; hf < 2; ++hf) {                      \
        const char* KsB = (const char*)Ks[(g) & 1][hf];                       \
        _Pragma("unroll") for (int kt = 0; kt < 4; ++kt) {                    \
          const bf16x8 k0f = *(const bf16x8*)(KsB + (kt * 16 + fr) * 128 + ((fg * 16) ^ swz)); \
          const bf16x8 k1f = *(const bf16x8*)(KsB + (kt * 16 + fr) * 128 + ((64 + fg * 16) ^ swz)); \
          f32x4 zz = {};                                                      \
          zz = mfma16(k0f, qf[0], zz);                                        \
          zz = mfma16(k1f, qf[1], zz);                                        \
          CUR[hf * 4 + kt] = zz;                                              \
        }                                                                     \
      }                                                                       \
      __builtin_amdgcn_s_setprio(0);                                          \
    }                                                                         \
    if ((g) == T0 - 1 || (g) == 16) {                                         \
      const int koff = ((g) == 16) ? koff1 : koff0;                           \
      _Pragma("unroll") for (int hf = 0; hf < 2; ++hf)                        \
        _Pragma("unroll") for (int kt = 0; kt < 4; ++kt)                      \
          _Pragma("unroll") for (int r = 0; r < 4; ++r)                       \
            if (hf * 64 + kt * 16 + kr + r > koff + w * 16 + fr)              \
              CUR[hf * 4 + kt][r] = -1e30f;                                   \
    }                                                                         \
    if ((g) > 0) {                                                            \
      SOFTMAX_PV(PREV, ((g) - 1) & 1);                                        \
      if ((g) == T0) {                                                        \
        store_o(j * 64);                                                      \
        _Pragma("unroll") for (int t = 0; t < 5; ++t)                         \
          _Pragma("unroll") for (int r = 0; r < 4; ++r) o[t][r] = 0.f;        \
        m_run = -1e30f;                                                       \
      }                                                                       \
    }                                                                         \
    __syncthreads();                                                          \
    if ((g) + 1 < 17) {                                                       \
      STAGE_V(((g) + 1) & 1, KK0((g) + 1));                                   \
      asm volatile("s_waitcnt vmcnt(4)" ::: "memory");                        \
    } else {                                                                  \
      asm volatile("s_waitcnt vmcnt(0)" ::: "memory");                        \
    }                                                                         \
  } while (0)

  auto store_o = [&](int qbase) {
    const float l = __shfl(o[4][0], fr);
    const float inv = 1.0f / l;
    const int s = qbase + w * 16 + fr;
#pragma unroll
    for (int t = 0; t < 4; ++t) {
      short4 ov = {to_bf16(o[t][0] * inv), to_bf16(o[t][1] * inv),
                   to_bf16(o[t][2] * inv), to_bf16(o[t][3] * inv)};
      *(short4*)(AO + (size_t)(b * SS + s) * D_MODEL + h * 64 + t * 16 + kr) = ov;
    }
  };

  STAGE_K(0, 0);
  STAGE_V(0, 0);
  asm volatile("s_waitcnt vmcnt(0)" ::: "memory");
  __syncthreads();

  for (int gg = 0; gg < 16; gg += 2) {
    STEP(stA, stB, gg);
    STEP(stB, stA, gg + 1);
  }
  STEP(stA, stB, 16);

  // epilogue: tile 16 lives in stA (17 is odd)
  SOFTMAX_PV(stA, 0);
  store_o((31 - j) * 64);
#undef STEP
#undef SOFTMAX_PV
#undef STAGE_K
#undef STAGE_V
#undef KK0
}

extern "C" void kernel_launch(void* const* d_in, const int* in_sizes, int n_in,
                              void* d_out, int out_size, void* d_ws, size_t ws_size,
                              hipStream_t stream) {
  const float* q  = (const float*)d_in[0];
  const float* k  = (const float*)d_in[1];
  const float* v  = (const float*)d_in[2];
  const float* Wq = (const float*)d_in[4];
  const float* bq = (const float*)d_in[5];
  const float* Wk = (const float*)d_in[6];
  const float* bk = (const float*)d_in[7];
  const float* Wv = (const float*)d_in[8];
  const float* bv = (const float*)d_in[9];
  const float* Wo = (const float*)d_in[10];
  const float* bo = (const float*)d_in[11];

  char* ws = (char*)d_ws;
  const size_t MB = 1u << 20;
  short* Xq = (short*)(ws + 0 * MB);   // Xq/Xk/Xv contiguous -> merged 12288x1024
  short* Xk = (short*)(ws + 8 * MB);
  short* Xv = (short*)(ws + 16 * MB);
  short* Bq = (short*)(ws + 24 * MB);
  short* Bk = (short*)(ws + 26 * MB);
  short* Bv = (short*)(ws + 28 * MB);
  short* Bo = (short*)(ws + 30 * MB);
  short* Qh = (short*)(ws + 32 * MB);
  short* Kh = (short*)(ws + 40 * MB);
  short* VT = (short*)(ws + 48 * MB);
  short* AO = (short*)(ws + 56 * MB);

  cvt7<<<dim3(MROWS * D_MODEL / 1024, 1, 7), 256, 0, stream>>>(
      q, k, v, Wq, Wk, Wv, Wo, Xq, Xk, Xv, Bq, Bk, Bv, Bo);

  gemm_qkv8<<<dim3(3 * MROWS / 256, D_MODEL / 256), 512, 0, stream>>>(
      Xq, Bq, Bk, Bv, bq, bk, bv, Qh, Kh, VT);

  attn_kernel<<<dim3(512), 256, 0, stream>>>(Qh, Kh, VT, AO);

  gemm_out<<<dim3(MROWS / 128, D_MODEL / 64), 256, 0, stream>>>(AO, Bo, bo, (float*)d_out);
}